// Round 8
// baseline (926.542 us; speedup 1.0000x reference)
//
#include <hip/hip_runtime.h>

typedef float f32x4 __attribute__((ext_vector_type(4)));
typedef __bf16 bf16x8 __attribute__((ext_vector_type(8)));
typedef unsigned int u32x4 __attribute__((ext_vector_type(4)));
typedef unsigned int u32x2 __attribute__((ext_vector_type(2)));
typedef unsigned short u16;

#define DEV __device__ __forceinline__

DEV u16 f2bf(float f) {
    unsigned int x = __float_as_uint(f);
    x += 0x7fffu + ((x >> 16) & 1u);   // round-to-nearest-even
    return (u16)(x >> 16);
}
DEV unsigned pk2(float a, float b) {
    return (unsigned)f2bf(a) | ((unsigned)f2bf(b) << 16);
}
DEV float elu(float x) { return x > 0.f ? x : expm1f(x); }

// async global->LDS, 16B/lane; LDS dest linear, swizzle on the global source.
DEV void gload16(const u16* g, void* l) {
    __builtin_amdgcn_global_load_lds(
        (const __attribute__((address_space(1))) unsigned int*)g,
        (__attribute__((address_space(3))) unsigned int*)l,
        16, 0, 0);
}

// coherent 16B load: bypass L1+L2, read at fabric/L3 (cross-XCD safe)
DEV u32x4 gload16cc(const u16* p) {
    u32x4 v;
    asm volatile("global_load_dwordx4 %0, %1, off sc0 sc1"
                 : "=v"(v) : "v"(p) : "memory");
    return v;
}

DEV float aload(const float* p) {
    return __hip_atomic_load(p, __ATOMIC_RELAXED, __HIP_MEMORY_SCOPE_AGENT);
}
DEV void astore(float* p, float v) {
    __hip_atomic_store(p, v, __ATOMIC_RELAXED, __HIP_MEMORY_SCOPE_AGENT);
}

// fence-free barrier: every wave drains its own vmem, then one lane arrives
// at a fabric counter and spins relaxed (no wbl2 / no buffer_inv).
DEV void barw(unsigned* ctr, unsigned cnt) {
    asm volatile("s_waitcnt vmcnt(0) lgkmcnt(0)" ::: "memory");
    __syncthreads();
    if (threadIdx.x == 0) {
        unsigned old = __hip_atomic_fetch_add(ctr, 1u, __ATOMIC_RELAXED,
                                              __HIP_MEMORY_SCOPE_AGENT);
        unsigned tgt = old - (old % cnt) + cnt;
        while (__hip_atomic_load(ctr, __ATOMIC_RELAXED,
                                 __HIP_MEMORY_SCOPE_AGENT) < tgt)
            __builtin_amdgcn_s_sleep(4);
    }
    __syncthreads();
}

constexpr float INV_M = 1.f / 16384.f;   // B*N
constexpr float EPSV  = 1e-5f;

// 256 blocks x 512 threads, 73728 B dynamic LDS.
__global__ __launch_bounds__(512) void k_mega(
        const float* __restrict__ in, const float* __restrict__ L,
        const float* __restrict__ mask, const float* __restrict__ W1,
        const float* __restrict__ b1, const float* __restrict__ Wb,
        const float* __restrict__ bblk, const float* __restrict__ gb,
        const float* __restrict__ beb, const float* __restrict__ g1,
        const float* __restrict__ be1, const float* __restrict__ g2,
        const float* __restrict__ be2, const float* __restrict__ W2,
        const float* __restrict__ b2,
        u16* __restrict__ Lb, u16* __restrict__ WT,
        float* __restrict__ xA, float* __restrict__ xB,
        u16* __restrict__ hT, float* __restrict__ SP0, float* __restrict__ SP1,
        unsigned* __restrict__ bar, float* __restrict__ poolP,
        float* __restrict__ maskP, float* __restrict__ out) {
    extern __shared__ char smem[];
    int t = threadIdx.x;
    int bid = blockIdx.x;
    int wg = ((bid & 7) << 5) | (bid >> 3);   // XCD swizzle
    int bb = wg >> 4, n0 = (wg & 15) << 6;
    int l = t & 63, w = t >> 6;               // 8 waves
    int wm = w >> 2, wn = w & 3;              // 2 x 4 wave grid
    int l16 = l & 15, ld16 = l >> 4;
    unsigned* barg = bar + 16 + (wg >> 5) * 16;   // per-group counters, 64B apart

    // ---------------- phase 0 ----------------
    {
        for (long v = (long)bid * 512 + t; v < 2097152; v += 131072) {
            long i = v * 8;
            f32x4 a = *(const f32x4*)(L + i);
            f32x4 b = *(const f32x4*)(L + i + 4);
            u32x4 pv;
            pv[0] = pk2(a[0], a[1]); pv[1] = pk2(a[2], a[3]);
            pv[2] = pk2(b[0], b[1]); pv[3] = pk2(b[2], b[3]);
            *(u32x4*)(Lb + i) = pv;
        }
        for (int o = bid * 512 + t; o < 245760; o += 131072) {
            int k = o >> 14, r = o & 16383, e = r >> 7, d = r & 127;
            WT[o] = f2bf(Wb[(k << 14) + (d << 7) + e]);
        }
        float* red0 = (float*)smem;            // [16][128]
        float* red1 = (float*)(smem + 8192);
        int c4 = (t & 31) * 4, rg = t >> 5;
        float w0[4], w1v[4], w2v[4], bb4[4];
#pragma unroll
        for (int c = 0; c < 4; ++c) {
            w0[c] = W1[c4 + c]; w1v[c] = W1[128 + c4 + c];
            w2v[c] = W1[256 + c4 + c]; bb4[c] = b1[c4 + c];
        }
        float s[4] = {}, q[4] = {};
        long R = (long)wg * 64;
#pragma unroll
        for (int i = 0; i < 4; ++i) {
            long grow = R + rg + 16 * i;
            float f0 = in[grow * 3], f1 = in[grow * 3 + 1], f2 = in[grow * 3 + 2];
            f32x4 v, z = {0.f, 0.f, 0.f, 0.f};
#pragma unroll
            for (int c = 0; c < 4; ++c) {
                float val = f0 * w0[c] + f1 * w1v[c] + f2 * w2v[c] + bb4[c];
                v[c] = val; s[c] += val; q[c] += val * val;
            }
            *(f32x4*)(xA + grow * 128 + c4) = v;
            *(f32x4*)(xB + grow * 128 + c4) = z;
        }
#pragma unroll
        for (int c = 0; c < 4; ++c) {
            red0[rg * 128 + c4 + c] = s[c]; red1[rg * 128 + c4 + c] = q[c];
        }
        __syncthreads();
        if (t < 128) {
            float a = 0;
#pragma unroll
            for (int g = 0; g < 16; ++g) a += red0[g * 128 + t];
            atomicAdd(&SP0[bb * 256 + t], a);
        } else if (t < 256) {
            int c = t - 128; float a = 0;
#pragma unroll
            for (int g = 0; g < 16; ++g) a += red1[g * 128 + c];
            atomicAdd(&SP0[bb * 256 + 128 + c], a);
        }
    }
    // flush Lb/WT to fabric so any XCD can read them; then global barrier
    __builtin_amdgcn_fence(__ATOMIC_RELEASE, "agent");
    barw(bar, 256);

    // ---------------- main loop ----------------
    float* pa = xA; float* pb = xB;
    for (int k = 0; k < 15; ++k) {
        float* spa = (k & 1) ? SP1 : SP0;
        float* spb = (k & 1) ? SP0 : SP1;

        // ---- phase A: stats finish + BN+ELU + @W_k -> hT ----
        {
            u16* Ws = (u16*)smem;               // [128][128] swz, 32KB
            u16* Hs = (u16*)(smem + 32768);     // [64][128] swz; reused CsT
            float* st = (float*)(smem + 49152);
            float* sc = (float*)(smem + 50176);
            float* sh = (float*)(smem + 50688);
            if (t < 256) {
                float s = 0.f;
#pragma unroll
                for (int i = 0; i < 16; ++i) s += aload(&spa[i * 256 + t]);
                st[t] = s;
            }
            if ((wg & 15) == 0 && t < 256) astore(&spb[bb * 256 + t], 0.f);
            const u32x4* wsrc = (const u32x4*)(WT + (size_t)k * 16384);
#pragma unroll
            for (int i = 0; i < 4; ++i) {
                int u = t + 512 * i;
                int r = u >> 4, sl = u & 15;
                *(u32x4*)((char*)Ws + r * 256 + ((sl ^ (r & 7)) << 4)) = wsrc[u];
            }
            __syncthreads();
            if (t < 128) {
                float mean = st[t] * INV_M, var = st[128 + t] * INV_M - mean * mean;
                float a = rsqrtf(var + EPSV) * gb[k * 128 + t];
                sc[t] = a; sh[t] = beb[k * 128 + t] - mean * a;
            }
            __syncthreads();
            const float* xb = pa + (long)wg * 8192;
#pragma unroll
            for (int i = 0; i < 4; ++i) {
                int idx = t + 512 * i;
                int row = idx >> 5, c4 = (idx & 31) * 4;
                f32x4 v = *(const f32x4*)(xb + row * 128 + c4);
                float h0 = elu(v[0] * sc[c4]     + sh[c4]);
                float h1 = elu(v[1] * sc[c4 + 1] + sh[c4 + 1]);
                float h2 = elu(v[2] * sc[c4 + 2] + sh[c4 + 2]);
                float h3 = elu(v[3] * sc[c4 + 3] + sh[c4 + 3]);
                u32x2 pw = {pk2(h0, h1), pk2(h2, h3)};
                *(u32x2*)((char*)Hs + row * 256 + ((c4 * 2) ^ ((row & 7) << 4))) = pw;
            }
            __syncthreads();
            f32x4 acc[2][2] = {};
#pragma unroll
            for (int ks = 0; ks < 4; ++ks) {
                int kb = ks * 64 + ld16 * 16;
                bf16x8 af[2], bfr[2];
#pragma unroll
                for (int m = 0; m < 2; ++m) {
                    int r = wm * 32 + m * 16 + l16;
                    af[m] = *(const bf16x8*)((char*)Hs + r * 256 + (kb ^ ((r & 7) << 4)));
                }
#pragma unroll
                for (int n = 0; n < 2; ++n) {
                    int e = wn * 32 + n * 16 + l16;
                    bfr[n] = *(const bf16x8*)((char*)Ws + e * 256 + (kb ^ ((e & 7) << 4)));
                }
#pragma unroll
                for (int m = 0; m < 2; ++m)
#pragma unroll
                    for (int n = 0; n < 2; ++n)
                        acc[m][n] = __builtin_amdgcn_mfma_f32_16x16x32_bf16(
                            af[m], bfr[n], acc[m][n], 0, 0, 0);
            }
            __syncthreads();
#pragma unroll
            for (int m = 0; m < 2; ++m)
#pragma unroll
                for (int n = 0; n < 2; ++n) {
                    int e = wn * 32 + n * 16 + l16;
                    int row0 = wm * 32 + m * 16 + ld16 * 4;
                    u32x2 pw = {pk2(acc[m][n][0], acc[m][n][1]),
                                pk2(acc[m][n][2], acc[m][n][3])};
                    *(u32x2*)((char*)Hs + e * 128 + ((row0 * 2) ^ ((e & 7) << 4))) = pw;
                }
            __syncthreads();
            {
                int e = t >> 2, sg = t & 3;
                const char* base = (const char*)Hs + e * 128;
                u16* orow = hT + ((long)(bb * 128 + e)) * 1024 + n0 + sg * 16;
#pragma unroll
                for (int u = 0; u < 2; ++u) {
                    u32x4 v = *(const u32x4*)(base + ((sg * 32 + u * 16) ^ ((e & 7) << 4)));
                    *(u32x4*)(orow + u * 8) = v;
                }
            }
        }
        // push hT to fabric, then group-local barrier (producers+consumers)
        __builtin_amdgcn_fence(__ATOMIC_RELEASE, "agent");
        barw(barg, 32);

        // ---- phase B: agg = L @ hw^T ; x update ; next stats ----
        {
            u16* AbL = (u16*)smem;                 // 3 x 8192 B
            u16* BbL = (u16*)(smem + 24576);       // 2 x 16384 B
            float* red = (float*)(smem + 57344);   // 8KB
            const u16* gA = Lb + ((long)(bb * 1024 + n0)) * 1024;
            const u16* gB = hT + (long)bb * 131072;
            long eB0 = t >> 3, eB1 = (t + 512) >> 3;
            int mg = t & 7;
            int wo0 = (int)eB0 * 128 + ((mg ^ ((int)eB0 & 7)) << 4);
            int wo1 = (int)eB1 * 128 + ((mg ^ ((int)eB1 & 7)) << 4);

#define STAGEA(buf, kt_) do { int rr = t >> 3, sl = t & 7;                    \
            gload16(gA + (long)rr * 1024 + (kt_) * 64 + ((sl ^ (rr & 7)) << 3), \
                    (char*)AbL + (buf) * 8192 + t * 16); } while (0)
#define LOADB(r0, r1, kt_) do {                                               \
            r0 = gload16cc(gB + eB0 * 1024 + (kt_) * 64 + mg * 8);            \
            r1 = gload16cc(gB + eB1 * 1024 + (kt_) * 64 + mg * 8); } while (0)

            u32x4 bE0, bE1, bO0, bO1;
            f32x4 acc[2][2] = {};
            LOADB(bE0, bE1, 0);
            STAGEA(0, 0);
            LOADB(bO0, bO1, 1);
            STAGEA(1, 1);
            asm volatile("s_waitcnt vmcnt(4)" : "+v"(bE0), "+v"(bE1) :: "memory");
            *(u32x4*)((char*)BbL + wo0) = bE0;
            *(u32x4*)((char*)BbL + wo1) = bE1;
            asm volatile("s_waitcnt lgkmcnt(0)" ::: "memory");
            __builtin_amdgcn_s_barrier();

#pragma unroll
            for (int kt = 0; kt < 16; ++kt) {
                if (kt <= 13) STAGEA((kt + 2) % 3, kt + 2);
                if (kt <= 14) {
                    if (kt & 1) {
                        if (kt == 1) asm volatile("s_waitcnt vmcnt(1)" : "+v"(bE0), "+v"(bE1) :: "memory");
                        else if (kt <= 13) asm volatile("s_waitcnt vmcnt(1)" : "+v"(bE0), "+v"(bE1) :: "memory");
                        char* wb = (char*)BbL + (((kt + 1) & 1)) * 16384;
                        *(u32x4*)(wb + wo0) = bE0;
                        *(u32x4*)(wb + wo1) = bE1;
                        if (kt <= 13) LOADB(bO0, bO1, kt + 2);
                    } else {
                        if (kt == 0) asm volatile("s_waitcnt vmcnt(2)" : "+v"(bO0), "+v"(bO1) :: "memory");
                        else if (kt <= 13) asm volatile("s_waitcnt vmcnt(1)" : "+v"(bO0), "+v"(bO1) :: "memory");
                        else asm volatile("s_waitcnt vmcnt(0)" : "+v"(bO0), "+v"(bO1) :: "memory");
                        char* wb = (char*)BbL + (((kt + 1) & 1)) * 16384;
                        *(u32x4*)(wb + wo0) = bO0;
                        *(u32x4*)(wb + wo1) = bO1;
                        if (kt <= 13) LOADB(bE0, bE1, kt + 2);
                    }
                }
                asm volatile("s_waitcnt lgkmcnt(0)" ::: "memory");
                __builtin_amdgcn_s_barrier();
                const char* Ab_ = (const char*)AbL + (kt % 3) * 8192;
                const char* Bb_ = (const char*)BbL + (kt & 1) * 16384;
                __builtin_amdgcn_s_setprio(1);
#pragma unroll
                for (int ks = 0; ks < 2; ++ks) {
                    int kb = ks * 64 + ld16 * 16;
                    bf16x8 af[2], bfr[2];
#pragma unroll
                    for (int m = 0; m < 2; ++m) {
                        int r = wm * 32 + m * 16 + l16;
                        af[m] = *(const bf16x8*)(Ab_ + r * 128 + (kb ^ ((r & 7) << 4)));
                    }
#pragma unroll
                    for (int n = 0; n < 2; ++n) {
                        int e = wn * 32 + n * 16 + l16;
                        bfr[n] = *(const bf16x8*)(Bb_ + e * 128 + (kb ^ ((e & 7) << 4)));
                    }
#pragma unroll
                    for (int m = 0; m < 2; ++m)
#pragma unroll
                        for (int n = 0; n < 2; ++n)
                            acc[m][n] = __builtin_amdgcn_mfma_f32_16x16x32_bf16(
                                af[m], bfr[n], acc[m][n], 0, 0, 0);
                }
                __builtin_amdgcn_s_setprio(0);
                __builtin_amdgcn_s_barrier();
            }
#undef STAGEA
#undef LOADB

            float* dst = pb + (long)wg * 8192;
#pragma unroll
            for (int n = 0; n < 2; ++n) {
                int e = wn * 32 + n * 16 + l16;
                float bv = bblk[k * 128 + e];
                float sv = 0.f, qv = 0.f;
#pragma unroll
                for (int m = 0; m < 2; ++m) {
                    int row0 = wm * 32 + m * 16 + ld16 * 4;
                    float* dp = dst + (long)row0 * 128 + e;
#pragma unroll
                    for (int j = 0; j < 4; ++j) {
                        float v = dp[j * 128] + acc[m][n][j] + bv;
                        dp[j * 128] = v;
                        sv += v; qv += v * v;
                    }
                }
                red[(wm * 4 + ld16) * 128 + e] = sv;
                red[(8 + wm * 4 + ld16) * 128 + e] = qv;
            }
            __syncthreads();
            if (t < 128) {
                float a = 0;
#pragma unroll
                for (int g = 0; g < 8; ++g) a += red[g * 128 + t];
                atomicAdd(&spb[bb * 256 + t], a);
            } else if (t < 256) {
                int c = t - 128; float a = 0;
#pragma unroll
                for (int g = 0; g < 8; ++g) a += red[(8 + g) * 128 + c];
                atomicAdd(&spb[bb * 256 + 128 + c], a);
            }
        }
        barw(bar, 256);           // stats global; x private; no fence needed
        float* tmp = pa; pa = pb; pb = tmp;
    }

    // ---------------- final: BN1+BN2+ELU+masked pool ----------------
    {
        float* sc1 = (float*)smem;
        float* sh1 = sc1 + 128;
        float* sc2 = sh1 + 128;
        float* sh2 = sc2 + 128;
        float* msk = (float*)(smem + 2048);
        float* fred = (float*)(smem + 4096);
        if (t < 256) {
            int which = t >> 7, c = t & 127;
            const float* p = which ? SP0 : SP1;
            float s = 0.f, q = 0.f;
#pragma unroll
            for (int i = 0; i < 16; ++i) {
                s += aload(&p[i * 256 + c]); q += aload(&p[i * 256 + 128 + c]);
            }
            float mean = s * INV_M, var = q * INV_M - mean * mean;
            float a = rsqrtf(var + EPSV) * (which ? g2[c] : g1[c]);
            (which ? sc2 : sc1)[c] = a;
            (which ? sh2 : sh1)[c] = (which ? be2[c] : be1[c]) - mean * a;
        } else if (t < 320) {
            msk[t - 256] = mask[bb * 1024 + n0 + (t - 256)];
        }
        __syncthreads();
        const float* xb1 = pa + (long)wg * 8192;
        const float* xb2 = pb + (long)wg * 8192;
        int row0 = t >> 5, c = (t & 31) * 4;
        f32x4 accv = {0.f, 0.f, 0.f, 0.f};
#pragma unroll
        for (int i = 0; i < 4; ++i) {
            int row = row0 + 16 * i;
            f32x4 v1 = *(const f32x4*)(xb1 + row * 128 + c);
            f32x4 v2 = *(const f32x4*)(xb2 + row * 128 + c);
            float m = msk[row];
            accv[0] += elu(v1[0]*sc1[c]   + sh1[c]   + v2[0]*sc2[c]   + sh2[c])   * m;
            accv[1] += elu(v1[1]*sc1[c+1] + sh1[c+1] + v2[1]*sc2[c+1] + sh2[c+1]) * m;
            accv[2] += elu(v1[2]*sc1[c+2] + sh1[c+2] + v2[2]*sc2[c+2] + sh2[c+2]) * m;
            accv[3] += elu(v1[3]*sc1[c+3] + sh1[c+3] + v2[3]*sc2[c+3] + sh2[c+3]) * m;
        }
        fred[row0 * 128 + c]     = accv[0];
        fred[row0 * 128 + c + 1] = accv[1];
        fred[row0 * 128 + c + 2] = accv[2];
        fred[row0 * 128 + c + 3] = accv[3];
        __syncthreads();
        if (t < 128) {
            float s = 0;
#pragma unroll
            for (int g = 0; g < 16; ++g) s += fred[g * 128 + t];
            astore(&poolP[wg * 128 + t], s);
        }
        if (t == 128) {
            float sm = 0;
#pragma unroll
            for (int j = 0; j < 64; ++j) sm += msk[j];
            astore(&maskP[wg], sm);
        }
    }
    barw(bar, 256);

    // ---------------- output: blocks with wg<16, one per batch ----------------
    if (wg < 16) {
        float* pooled = (float*)smem;
        if (t < 128) {
            float s = 0.f;
            for (int tl = 0; tl < 16; ++tl) s += aload(&poolP[(wg * 16 + tl) * 128 + t]);
            pooled[t] = s;
        }
        if (t == 128) {
            float sm = 0.f;
            for (int tl = 0; tl < 16; ++tl) sm += aload(&maskP[wg * 16 + tl]);
            pooled[128] = 1.f / sm;
        }
        __syncthreads();
        if (t < 128) {
            float acc = 0.f, inv = pooled[128];
            for (int d = 0; d < 128; ++d) acc += pooled[d] * W2[d * 128 + t];
            out[wg * 128 + t] = acc * inv + b2[t];
        }
    }
}

// ---------------- host launcher ----------------

extern "C" void kernel_launch(void* const* d_in, const int* in_sizes, int n_in,
                              void* d_out, int out_size, void* d_ws, size_t ws_size,
                              hipStream_t stream) {
    const float* inputs = (const float*)d_in[0];
    const float* L      = (const float*)d_in[1];
    const float* mask   = (const float*)d_in[2];
    const float* W1     = (const float*)d_in[3];
    const float* b1     = (const float*)d_in[4];
    const float* Wb     = (const float*)d_in[5];
    const float* bblk   = (const float*)d_in[6];
    const float* gb     = (const float*)d_in[7];
    const float* beb    = (const float*)d_in[8];
    const float* g1     = (const float*)d_in[9];
    const float* be1    = (const float*)d_in[10];
    const float* g2     = (const float*)d_in[11];
    const float* be2    = (const float*)d_in[12];
    const float* W2     = (const float*)d_in[13];
    const float* b2     = (const float*)d_in[14];
    float* out = (float*)d_out;

    char* ws = (char*)d_ws;
    u16*      Lb    = (u16*)(ws);                      // 33554432 B
    u16*      WT    = (u16*)(ws + 33554432);           // 491520
    float*    xA    = (float*)(ws + 34045952);         // 8388608
    float*    xB    = (float*)(ws + 42434560);         // 8388608
    u16*      hT    = (u16*)(ws + 50823168);           // 4194304
    float*    poolP = (float*)(ws + 50823168);         // overlays hT (dead by then)
    float*    maskP = (float*)(ws + 50823168 + 131072);
    float*    SP0   = (float*)(ws + 55017472);         // 16384
    float*    SP1   = (float*)(ws + 55017472 + 16384); // 16384
    unsigned* bar   = (unsigned*)(ws + 55017472 + 32768);

    hipMemsetAsync(ws + 55017472, 0, 32768 + 1024, stream);

    hipLaunchKernelGGL(k_mega, dim3(256), dim3(512), 73728, stream,
                       inputs, L, mask, W1, b1, Wb, bblk, gb, beb,
                       g1, be1, g2, be2, W2, b2,
                       Lb, WT, xA, xB, hT, SP0, SP1, bar, poolP, maskP, out);
}

// Round 9
// 414.065 us; speedup vs baseline: 2.2377x; 2.2377x over previous
//
#include <hip/hip_runtime.h>

typedef float f32x4 __attribute__((ext_vector_type(4)));
typedef __bf16 bf16x8 __attribute__((ext_vector_type(8)));
typedef unsigned int u32x4 __attribute__((ext_vector_type(4)));
typedef unsigned int u32x2 __attribute__((ext_vector_type(2)));
typedef unsigned short u16;

#define DEV __device__ __forceinline__

DEV u16 f2bf(float f) {
    unsigned int x = __float_as_uint(f);
    x += 0x7fffu + ((x >> 16) & 1u);   // round-to-nearest-even
    return (u16)(x >> 16);
}
DEV unsigned pk2(float a, float b) {
    return (unsigned)f2bf(a) | ((unsigned)f2bf(b) << 16);
}
DEV float elu(float x) { return x > 0.f ? x : expm1f(x); }

// async global->LDS, 16B/lane; LDS dest linear, swizzle on the global source.
DEV void gload16(const u16* g, void* l) {
    __builtin_amdgcn_global_load_lds(
        (const __attribute__((address_space(1))) unsigned int*)g,
        (__attribute__((address_space(3))) unsigned int*)l,
        16, 0, 0);
}

DEV float aload(const float* p) {
    return __hip_atomic_load(p, __ATOMIC_RELAXED, __HIP_MEMORY_SCOPE_AGENT);
}
DEV void astore(float* p, float v) {
    __hip_atomic_store(p, v, __ATOMIC_RELAXED, __HIP_MEMORY_SCOPE_AGENT);
}

// fence-free grid barrier (proven r7/r8): drain own vmem, arrive at fabric
// counter, spin relaxed. No wbl2 / no buffer_inv anywhere.
DEV void barw(unsigned* ctr, unsigned cnt) {
    asm volatile("s_waitcnt vmcnt(0) lgkmcnt(0)" ::: "memory");
    __syncthreads();
    if (threadIdx.x == 0) {
        unsigned old = __hip_atomic_fetch_add(ctr, 1u, __ATOMIC_RELAXED,
                                              __HIP_MEMORY_SCOPE_AGENT);
        unsigned tgt = old - (old % cnt) + cnt;
        while (__hip_atomic_load(ctr, __ATOMIC_RELAXED,
                                 __HIP_MEMORY_SCOPE_AGENT) < tgt)
            __builtin_amdgcn_s_sleep(4);
    }
    __syncthreads();
}

constexpr float INV_M = 1.f / 16384.f;   // B*N
constexpr float EPSV  = 1e-5f;

// One launch per iteration: [phase B(k-1) | barw | phase A(k)].
// k=0: phase0 (cvt L, cvt W, init) | fence+barw | A(0)
// k=1..14: B(k-1) | barw | A(k)
// k=15: B(14) | barw | final pool | barw | out
// hT handoff (A->B) always crosses a LAUNCH boundary (free coherence).
__global__ __launch_bounds__(512) void k_iter(
        int k,
        const float* __restrict__ in, const float* __restrict__ L,
        const float* __restrict__ mask, const float* __restrict__ W1,
        const float* __restrict__ b1, const float* __restrict__ Wb,
        const float* __restrict__ bblk, const float* __restrict__ gb,
        const float* __restrict__ beb, const float* __restrict__ g1,
        const float* __restrict__ be1, const float* __restrict__ g2,
        const float* __restrict__ be2, const float* __restrict__ W2,
        const float* __restrict__ b2,
        u16* __restrict__ Lb, u16* __restrict__ WT,
        float* __restrict__ xA, float* __restrict__ xB,
        u16* __restrict__ hT, float* __restrict__ SP0, float* __restrict__ SP1,
        unsigned* __restrict__ bar, float* __restrict__ poolP,
        float* __restrict__ maskP, float* __restrict__ out) {
    extern __shared__ char smem[];
    int t = threadIdx.x;
    int bid = blockIdx.x;
    int wg = ((bid & 7) << 5) | (bid >> 3);   // XCD swizzle (perf only)
    int bb = wg >> 4, n0 = (wg & 15) << 6;
    int l = t & 63, w = t >> 6;               // 8 waves
    int wm = w >> 2, wn = w & 3;              // 2 x 4 wave grid
    int l16 = l & 15, ld16 = l >> 4;

    // x buffer this launch operates on (in-place carry update):
    float* xcur = (k & 1) ? xB : xA;
    // stats: B(k-1) adds into SP[k&1]; A(k) reads SP[k&1]
    float* spa = (k & 1) ? SP1 : SP0;
    float* spz = (k & 1) ? SP0 : SP1;        // zeroed for next launch's B(k)

    if (k == 0) {
        // ---------------- phase 0: conversions + init ----------------
        for (long v = (long)bid * 512 + t; v < 2097152; v += 131072) {
            long i = v * 8;
            f32x4 a = *(const f32x4*)(L + i);
            f32x4 b = *(const f32x4*)(L + i + 4);
            u32x4 pv;
            pv[0] = pk2(a[0], a[1]); pv[1] = pk2(a[2], a[3]);
            pv[2] = pk2(b[0], b[1]); pv[3] = pk2(b[2], b[3]);
            *(u32x4*)(Lb + i) = pv;
        }
        for (int o = bid * 512 + t; o < 245760; o += 131072) {
            int kk = o >> 14, r = o & 16383, e = r >> 7, d = r & 127;
            WT[o] = f2bf(Wb[(kk << 14) + (d << 7) + e]);
        }
        float* red0 = (float*)smem;            // [16][128]
        float* red1 = (float*)(smem + 8192);
        int c4 = (t & 31) * 4, rg = t >> 5;
        float w0[4], w1v[4], w2v[4], bb4[4];
#pragma unroll
        for (int c = 0; c < 4; ++c) {
            w0[c] = W1[c4 + c]; w1v[c] = W1[128 + c4 + c];
            w2v[c] = W1[256 + c4 + c]; bb4[c] = b1[c4 + c];
        }
        float s[4] = {}, q[4] = {};
        long R = (long)wg * 64;
#pragma unroll
        for (int i = 0; i < 4; ++i) {
            long grow = R + rg + 16 * i;
            float f0 = in[grow * 3], f1 = in[grow * 3 + 1], f2 = in[grow * 3 + 2];
            f32x4 v, z = {0.f, 0.f, 0.f, 0.f};
#pragma unroll
            for (int c = 0; c < 4; ++c) {
                float val = f0 * w0[c] + f1 * w1v[c] + f2 * w2v[c] + bb4[c];
                v[c] = val; s[c] += val; q[c] += val * val;
            }
            *(f32x4*)(xA + grow * 128 + c4) = v;
            *(f32x4*)(xB + grow * 128 + c4) = z;
        }
#pragma unroll
        for (int c = 0; c < 4; ++c) {
            red0[rg * 128 + c4 + c] = s[c]; red1[rg * 128 + c4 + c] = q[c];
        }
        __syncthreads();
        if (t < 128) {
            float a = 0;
#pragma unroll
            for (int g = 0; g < 16; ++g) a += red0[g * 128 + t];
            atomicAdd(&SP0[bb * 256 + t], a);
        } else if (t < 256) {
            int c = t - 128; float a = 0;
#pragma unroll
            for (int g = 0; g < 16; ++g) a += red1[g * 128 + c];
            atomicAdd(&SP0[bb * 256 + 128 + c], a);
        }
        // one-time flush so WT/Lb (cross-block plain stores) reach fabric
        __builtin_amdgcn_fence(__ATOMIC_RELEASE, "agent");
        barw(bar, 256);
    } else {
        // ---------------- phase B(k-1): agg = L @ hT^T ; x update ----------------
        u16* As = (u16*)smem;                  // 3 x 8192 B
        u16* Bs = (u16*)(smem + 24576);        // 3 x 16384 B
        float* red = (float*)(smem + 73728);   // 8KB
        const u16* gA = Lb + ((long)(bb * 1024 + n0)) * 1024;
        const u16* gB = hT + (long)bb * 131072;

        // zero the other-parity stats buffer for NEXT launch's phase B
        if (k <= 14 && (wg & 15) == 0 && t < 256) astore(&spz[bb * 256 + t], 0.f);

#define STAGE(buf, kt_) do {                                                  \
        int k0_ = (kt_) * 64;                                                 \
        { int u = t; int r = u >> 3, sl = u & 7;                              \
          gload16(gA + (long)r * 1024 + k0_ + ((sl ^ (r & 7)) << 3),          \
                  (char*)As + (buf) * 8192 + u * 16); }                       \
        _Pragma("unroll")                                                     \
        for (int j = 0; j < 2; ++j) {                                         \
            int u = t + 512 * j; int r = u >> 3, sl = u & 7;                  \
            gload16(gB + (long)r * 1024 + k0_ + ((sl ^ (r & 7)) << 3),        \
                    (char*)Bs + (buf) * 16384 + u * 16);                      \
        }                                                                     \
    } while (0)

        f32x4 acc[2][2] = {};
        STAGE(0, 0);
        STAGE(1, 1);
        asm volatile("s_waitcnt vmcnt(3)" ::: "memory");
        __builtin_amdgcn_s_barrier();

        for (int kt = 0; kt < 16; ++kt) {
            if (kt <= 13) STAGE((kt + 2) % 3, kt + 2);
            const char* Ab = (const char*)As + (kt % 3) * 8192;
            const char* Bb = (const char*)Bs + (kt % 3) * 16384;
            __builtin_amdgcn_s_setprio(1);
#pragma unroll
            for (int ks = 0; ks < 2; ++ks) {
                int kb = ks * 64 + ld16 * 16;
                bf16x8 af[2], bfr[2];
#pragma unroll
                for (int m = 0; m < 2; ++m) {
                    int r = wm * 32 + m * 16 + l16;
                    af[m] = *(const bf16x8*)(Ab + r * 128 + (kb ^ ((r & 7) << 4)));
                }
#pragma unroll
                for (int n = 0; n < 2; ++n) {
                    int e = wn * 32 + n * 16 + l16;
                    bfr[n] = *(const bf16x8*)(Bb + e * 128 + (kb ^ ((e & 7) << 4)));
                }
#pragma unroll
                for (int m = 0; m < 2; ++m)
#pragma unroll
                    for (int n = 0; n < 2; ++n)
                        acc[m][n] = __builtin_amdgcn_mfma_f32_16x16x32_bf16(
                            af[m], bfr[n], acc[m][n], 0, 0, 0);
            }
            __builtin_amdgcn_s_setprio(0);
            if (kt <= 13) {
                asm volatile("s_waitcnt vmcnt(3)" ::: "memory");
                __builtin_amdgcn_s_barrier();
            } else if (kt == 14) {
                asm volatile("s_waitcnt vmcnt(0)" ::: "memory");
                __builtin_amdgcn_s_barrier();
            }
        }
#undef STAGE

        // epilogue: x1_new = x2_old + agg + bias ; stats partials
        float* dst = xcur + (long)wg * 8192;
        const float* biasv = bblk + (k - 1) * 128;
#pragma unroll
        for (int n = 0; n < 2; ++n) {
            int e = wn * 32 + n * 16 + l16;
            float bv = biasv[e];
            float sv = 0.f, qv = 0.f;
#pragma unroll
            for (int m = 0; m < 2; ++m) {
                int row0 = wm * 32 + m * 16 + ld16 * 4;
                float* dp = dst + (long)row0 * 128 + e;
#pragma unroll
                for (int j = 0; j < 4; ++j) {
                    float v = dp[j * 128] + acc[m][n][j] + bv;
                    dp[j * 128] = v;
                    sv += v; qv += v * v;
                }
            }
            red[(wm * 4 + ld16) * 128 + e] = sv;
            red[(8 + wm * 4 + ld16) * 128 + e] = qv;
        }
        __syncthreads();
        if (t < 128) {
            float a = 0;
#pragma unroll
            for (int g = 0; g < 8; ++g) a += red[g * 128 + t];
            atomicAdd(&spa[bb * 256 + t], a);
        } else if (t < 256) {
            int c = t - 128; float a = 0;
#pragma unroll
            for (int g = 0; g < 8; ++g) a += red[(8 + g) * 128 + c];
            atomicAdd(&spa[bb * 256 + 128 + c], a);
        }
        barw(bar, 256);
    }

    if (k < 15) {
        // ---------------- phase A(k): stats + BN+ELU + @W_k -> hT ----------------
        u16* Ws = (u16*)smem;               // [128][128] swz, 32KB
        u16* Hs = (u16*)(smem + 32768);     // [64][128] swz; reused CsT
        float* st = (float*)(smem + 49152);
        float* sc = (float*)(smem + 50176);
        float* sh = (float*)(smem + 50688);
        if (t < 256) {
            float s = 0.f;
#pragma unroll
            for (int i = 0; i < 16; ++i) s += aload(&spa[i * 256 + t]);
            st[t] = s;
        }
        const u32x4* wsrc = (const u32x4*)(WT + (size_t)k * 16384);
#pragma unroll
        for (int i = 0; i < 4; ++i) {
            int u = t + 512 * i;
            int r = u >> 4, sl = u & 15;
            *(u32x4*)((char*)Ws + r * 256 + ((sl ^ (r & 7)) << 4)) = wsrc[u];
        }
        __syncthreads();
        if (t < 128) {
            float mean = st[t] * INV_M, var = st[128 + t] * INV_M - mean * mean;
            float a = rsqrtf(var + EPSV) * gb[k * 128 + t];
            sc[t] = a; sh[t] = beb[k * 128 + t] - mean * a;
        }
        __syncthreads();
        const float* xb = xcur + (long)wg * 8192;
#pragma unroll
        for (int i = 0; i < 4; ++i) {
            int idx = t + 512 * i;
            int row = idx >> 5, c4 = (idx & 31) * 4;
            f32x4 v = *(const f32x4*)(xb + row * 128 + c4);
            float h0 = elu(v[0] * sc[c4]     + sh[c4]);
            float h1 = elu(v[1] * sc[c4 + 1] + sh[c4 + 1]);
            float h2 = elu(v[2] * sc[c4 + 2] + sh[c4 + 2]);
            float h3 = elu(v[3] * sc[c4 + 3] + sh[c4 + 3]);
            u32x2 pw = {pk2(h0, h1), pk2(h2, h3)};
            *(u32x2*)((char*)Hs + row * 256 + ((c4 * 2) ^ ((row & 7) << 4))) = pw;
        }
        __syncthreads();
        f32x4 acc[2][2] = {};
#pragma unroll
        for (int ks = 0; ks < 4; ++ks) {
            int kb = ks * 64 + ld16 * 16;
            bf16x8 af[2], bfr[2];
#pragma unroll
            for (int m = 0; m < 2; ++m) {
                int r = wm * 32 + m * 16 + l16;
                af[m] = *(const bf16x8*)((char*)Hs + r * 256 + (kb ^ ((r & 7) << 4)));
            }
#pragma unroll
            for (int n = 0; n < 2; ++n) {
                int e = wn * 32 + n * 16 + l16;
                bfr[n] = *(const bf16x8*)((char*)Ws + e * 256 + (kb ^ ((e & 7) << 4)));
            }
#pragma unroll
            for (int m = 0; m < 2; ++m)
#pragma unroll
                for (int n = 0; n < 2; ++n)
                    acc[m][n] = __builtin_amdgcn_mfma_f32_16x16x32_bf16(
                        af[m], bfr[n], acc[m][n], 0, 0, 0);
        }
        __syncthreads();
#pragma unroll
        for (int m = 0; m < 2; ++m)
#pragma unroll
            for (int n = 0; n < 2; ++n) {
                int e = wn * 32 + n * 16 + l16;
                int row0 = wm * 32 + m * 16 + ld16 * 4;
                u32x2 pw = {pk2(acc[m][n][0], acc[m][n][1]),
                            pk2(acc[m][n][2], acc[m][n][3])};
                *(u32x2*)((char*)Hs + e * 128 + ((row0 * 2) ^ ((e & 7) << 4))) = pw;
            }
        __syncthreads();
        {
            int e = t >> 2, sg = t & 3;
            const char* base = (const char*)Hs + e * 128;
            u16* orow = hT + ((long)(bb * 128 + e)) * 1024 + n0 + sg * 16;
#pragma unroll
            for (int u = 0; u < 2; ++u) {
                u32x4 v = *(const u32x4*)(base + ((sg * 32 + u * 16) ^ ((e & 7) << 4)));
                *(u32x4*)(orow + u * 8) = v;
            }
        }
    } else {
        // ---------------- final: BN1+BN2+ELU+masked pool + out ----------------
        float* x1p = xcur;                       // k=15 odd -> xB holds x1
        float* x2p = (k & 1) ? xA : xB;          // xA holds x2
        float* sc1 = (float*)smem;
        float* sh1 = sc1 + 128;
        float* sc2 = sh1 + 128;
        float* sh2 = sc2 + 128;
        float* msk = (float*)(smem + 2048);
        float* fred = (float*)(smem + 4096);
        if (t < 256) {
            int which = t >> 7, c = t & 127;
            const float* p = which ? SP0 : SP1;  // x1 stats in SP1, x2 in SP0
            float s = 0.f, q = 0.f;
#pragma unroll
            for (int i = 0; i < 16; ++i) {
                s += aload(&p[i * 256 + c]); q += aload(&p[i * 256 + 128 + c]);
            }
            float mean = s * INV_M, var = q * INV_M - mean * mean;
            float a = rsqrtf(var + EPSV) * (which ? g2[c] : g1[c]);
            (which ? sc2 : sc1)[c] = a;
            (which ? sh2 : sh1)[c] = (which ? be2[c] : be1[c]) - mean * a;
        } else if (t < 320) {
            msk[t - 256] = mask[bb * 1024 + n0 + (t - 256)];
        }
        __syncthreads();
        const float* xb1 = x1p + (long)wg * 8192;
        const float* xb2 = x2p + (long)wg * 8192;
        int row0 = t >> 5, c = (t & 31) * 4;
        f32x4 accv = {0.f, 0.f, 0.f, 0.f};
#pragma unroll
        for (int i = 0; i < 4; ++i) {
            int row = row0 + 16 * i;
            f32x4 v1 = *(const f32x4*)(xb1 + row * 128 + c);
            f32x4 v2 = *(const f32x4*)(xb2 + row * 128 + c);
            float m = msk[row];
            accv[0] += elu(v1[0]*sc1[c]   + sh1[c]   + v2[0]*sc2[c]   + sh2[c])   * m;
            accv[1] += elu(v1[1]*sc1[c+1] + sh1[c+1] + v2[1]*sc2[c+1] + sh2[c+1]) * m;
            accv[2] += elu(v1[2]*sc1[c+2] + sh1[c+2] + v2[2]*sc2[c+2] + sh2[c+2]) * m;
            accv[3] += elu(v1[3]*sc1[c+3] + sh1[c+3] + v2[3]*sc2[c+3] + sh2[c+3]) * m;
        }
        fred[row0 * 128 + c]     = accv[0];
        fred[row0 * 128 + c + 1] = accv[1];
        fred[row0 * 128 + c + 2] = accv[2];
        fred[row0 * 128 + c + 3] = accv[3];
        __syncthreads();
        if (t < 128) {
            float s = 0;
#pragma unroll
            for (int g = 0; g < 16; ++g) s += fred[g * 128 + t];
            astore(&poolP[wg * 128 + t], s);
        }
        if (t == 128) {
            float sm = 0;
#pragma unroll
            for (int j = 0; j < 64; ++j) sm += msk[j];
            astore(&maskP[wg], sm);
        }
        barw(bar, 256);
        if (wg < 16) {
            float* pooled = (float*)smem;
            __syncthreads();
            if (t < 128) {
                float s = 0.f;
                for (int tl = 0; tl < 16; ++tl)
                    s += aload(&poolP[(wg * 16 + tl) * 128 + t]);
                pooled[t] = s;
            }
            if (t == 128) {
                float sm = 0.f;
                for (int tl = 0; tl < 16; ++tl) sm += aload(&maskP[wg * 16 + tl]);
                pooled[128] = 1.f / sm;
            }
            __syncthreads();
            if (t < 128) {
                float acc = 0.f, inv = pooled[128];
                for (int d = 0; d < 128; ++d) acc += pooled[d] * W2[d * 128 + t];
                out[wg * 128 + t] = acc * inv + b2[t];
            }
        }
    }
}

// ---------------- host launcher ----------------

extern "C" void kernel_launch(void* const* d_in, const int* in_sizes, int n_in,
                              void* d_out, int out_size, void* d_ws, size_t ws_size,
                              hipStream_t stream) {
    const float* inputs = (const float*)d_in[0];
    const float* L      = (const float*)d_in[1];
    const float* mask   = (const float*)d_in[2];
    const float* W1     = (const float*)d_in[3];
    const float* b1     = (const float*)d_in[4];
    const float* Wb     = (const float*)d_in[5];
    const float* bblk   = (const float*)d_in[6];
    const float* gb     = (const float*)d_in[7];
    const float* beb    = (const float*)d_in[8];
    const float* g1     = (const float*)d_in[9];
    const float* be1    = (const float*)d_in[10];
    const float* g2     = (const float*)d_in[11];
    const float* be2    = (const float*)d_in[12];
    const float* W2     = (const float*)d_in[13];
    const float* b2     = (const float*)d_in[14];
    float* out = (float*)d_out;

    char* ws = (char*)d_ws;
    u16*      Lb    = (u16*)(ws);                      // 33554432 B
    u16*      WT    = (u16*)(ws + 33554432);           // 491520
    float*    xA    = (float*)(ws + 34045952);         // 8388608
    float*    xB    = (float*)(ws + 42434560);         // 8388608
    u16*      hT    = (u16*)(ws + 50823168);           // 4194304
    float*    poolP = (float*)(ws + 50823168);         // overlays hT (dead by then)
    float*    maskP = (float*)(ws + 50823168 + 131072);
    float*    SP0   = (float*)(ws + 55017472);         // 16384
    float*    SP1   = (float*)(ws + 55017472 + 16384); // 16384
    unsigned* bar   = (unsigned*)(ws + 55017472 + 32768);

    // zero SP0, SP1, barrier counter (in-graph, runs every replay)
    hipMemsetAsync(ws + 55017472, 0, 32768 + 1024, stream);

    for (int k = 0; k <= 15; ++k) {
        hipLaunchKernelGGL(k_iter, dim3(256), dim3(512), 81920, stream, k,
                           inputs, L, mask, W1, b1, Wb, bblk, gb, beb,
                           g1, be1, g2, be2, W2, b2,
                           Lb, WT, xA, xB, hT, SP0, SP1, bar, poolP, maskP, out);
    }
}

// Round 10
// 356.249 us; speedup vs baseline: 2.6008x; 1.1623x over previous
//
#include <hip/hip_runtime.h>

typedef float f32x4 __attribute__((ext_vector_type(4)));
typedef __bf16 bf16x8 __attribute__((ext_vector_type(8)));
typedef unsigned int u32x4 __attribute__((ext_vector_type(4)));
typedef unsigned int u32x2 __attribute__((ext_vector_type(2)));
typedef unsigned short u16;

#define DEV __device__ __forceinline__

DEV u16 f2bf(float f) {
    unsigned int x = __float_as_uint(f);
    x += 0x7fffu + ((x >> 16) & 1u);   // round-to-nearest-even
    return (u16)(x >> 16);
}
DEV unsigned pk2(float a, float b) {
    return (unsigned)f2bf(a) | ((unsigned)f2bf(b) << 16);
}
DEV float elu(float x) { return x > 0.f ? x : expm1f(x); }

// async global->LDS, 16B/lane; LDS dest linear, swizzle on the global source.
DEV void gload16(const u16* g, void* l) {
    __builtin_amdgcn_global_load_lds(
        (const __attribute__((address_space(1))) unsigned int*)g,
        (__attribute__((address_space(3))) unsigned int*)l,
        16, 0, 0);
}

DEV float aload(const float* p) {
    return __hip_atomic_load(p, __ATOMIC_RELAXED, __HIP_MEMORY_SCOPE_AGENT);
}
DEV void astore(float* p, float v) {
    __hip_atomic_store(p, v, __ATOMIC_RELAXED, __HIP_MEMORY_SCOPE_AGENT);
}

// fence-free grid barrier (proven r7-r9): drain own vmem, arrive at fabric
// counter, spin relaxed. No wbl2 / no buffer_inv anywhere.
DEV void barw(unsigned* ctr, unsigned cnt) {
    asm volatile("s_waitcnt vmcnt(0) lgkmcnt(0)" ::: "memory");
    __syncthreads();
    if (threadIdx.x == 0) {
        unsigned old = __hip_atomic_fetch_add(ctr, 1u, __ATOMIC_RELAXED,
                                              __HIP_MEMORY_SCOPE_AGENT);
        unsigned tgt = old - (old % cnt) + cnt;
        while (__hip_atomic_load(ctr, __ATOMIC_RELAXED,
                                 __HIP_MEMORY_SCOPE_AGENT) < tgt)
            __builtin_amdgcn_s_sleep(4);
    }
    __syncthreads();
}

constexpr float INV_M = 1.f / 16384.f;   // B*N
constexpr float EPSV  = 1e-5f;

// ---------------- wide prep: L->bf16, W->WT, init+stats ----------------
// 2048 blocks x 256 thr, full occupancy streaming (fixes r9's 95us k=0).
__global__ __launch_bounds__(256) void k_prep(
        const float* __restrict__ in, const float* __restrict__ L,
        const float* __restrict__ W1, const float* __restrict__ b1,
        const float* __restrict__ Wb,
        u16* __restrict__ Lb, u16* __restrict__ WT,
        float* __restrict__ xA, float* __restrict__ xB,
        float* __restrict__ SP0) {
    int t = threadIdx.x, bid = blockIdx.x;
    // L -> bf16: 1024 f32x8 vectors per block (2048*1024 = 2,097,152 total)
    {
        long base = (long)bid * 1024;
#pragma unroll
        for (int j = 0; j < 4; ++j) {
            long i = (base + j * 256 + t) * 8;
            f32x4 a = *(const f32x4*)(L + i);
            f32x4 b = *(const f32x4*)(L + i + 4);
            u32x4 v;
            v[0] = pk2(a[0], a[1]); v[1] = pk2(a[2], a[3]);
            v[2] = pk2(b[0], b[1]); v[3] = pk2(b[2], b[3]);
            *(u32x4*)(Lb + i) = v;
        }
    }
    // W_blocks [15][d][e] -> WT [15][e][d]
    if (bid < 960) {
        int o = bid * 256 + t;
        int kk = o >> 14, r = o & 16383, e = r >> 7, d = r & 127;
        WT[o] = f2bf(Wb[(kk << 14) + (d << 7) + e]);
    }
    // init: x1 = in@W1 + b1, x2 = 0, stats -> SP0 (blocks 1024..1279, 64 rows each)
    if (bid >= 1024 && bid < 1280) {
        __shared__ float red[2][8][128];
        int ib = bid - 1024;
        long R = (long)ib * 64;
        int c4 = (t & 31) * 4, rg = t >> 5;
        float w0[4], w1v[4], w2v[4], bb4[4];
#pragma unroll
        for (int c = 0; c < 4; ++c) {
            w0[c] = W1[c4 + c]; w1v[c] = W1[128 + c4 + c];
            w2v[c] = W1[256 + c4 + c]; bb4[c] = b1[c4 + c];
        }
        float s[4] = {}, q[4] = {};
#pragma unroll
        for (int i = 0; i < 8; ++i) {
            long grow = R + rg + 8 * i;
            float f0 = in[grow * 3], f1 = in[grow * 3 + 1], f2 = in[grow * 3 + 2];
            f32x4 v, z = {0.f, 0.f, 0.f, 0.f};
#pragma unroll
            for (int c = 0; c < 4; ++c) {
                float val = f0 * w0[c] + f1 * w1v[c] + f2 * w2v[c] + bb4[c];
                v[c] = val; s[c] += val; q[c] += val * val;
            }
            *(f32x4*)(xA + grow * 128 + c4) = v;
            *(f32x4*)(xB + grow * 128 + c4) = z;
        }
#pragma unroll
        for (int c = 0; c < 4; ++c) { red[0][rg][c4 + c] = s[c]; red[1][rg][c4 + c] = q[c]; }
        __syncthreads();
        if (t < 128) {
            float a = 0;
#pragma unroll
            for (int g = 0; g < 8; ++g) a += red[0][g][t];
            atomicAdd(&SP0[(ib & 15) * 256 + t], a);
        } else {
            int c = t - 128; float a = 0;
#pragma unroll
            for (int g = 0; g < 8; ++g) a += red[1][g][c];
            atomicAdd(&SP0[(ib & 15) * 256 + 128 + c], a);
        }
    }
}

// One launch per iteration: [phase B(k-1) | barw | phase A(k)].
// k=0: A(0) only (prep provided stats/x via launch boundary)
// k=1..14: B(k-1) | barw | A(k)
// k=15: B(14) | barw | final pool | barw | out
// hT handoff (A->B) always crosses a LAUNCH boundary (free coherence).
__global__ __launch_bounds__(512) void k_iter(
        int k,
        const float* __restrict__ mask, const float* __restrict__ bblk,
        const float* __restrict__ gb, const float* __restrict__ beb,
        const float* __restrict__ g1, const float* __restrict__ be1,
        const float* __restrict__ g2, const float* __restrict__ be2,
        const float* __restrict__ W2, const float* __restrict__ b2,
        const u16* __restrict__ Lb, const u16* __restrict__ WT,
        float* __restrict__ xA, float* __restrict__ xB,
        u16* __restrict__ hT, float* __restrict__ SP0, float* __restrict__ SP1,
        unsigned* __restrict__ bar, float* __restrict__ poolP,
        float* __restrict__ maskP, float* __restrict__ out) {
    extern __shared__ char smem[];
    int t = threadIdx.x;
    int bid = blockIdx.x;
    int wg = ((bid & 7) << 5) | (bid >> 3);   // XCD swizzle (perf only)
    int bb = wg >> 4, n0 = (wg & 15) << 6;
    int l = t & 63, w = t >> 6;               // 8 waves
    int wm = w >> 2, wn = w & 3;              // 2 x 4 wave grid
    int l16 = l & 15, ld16 = l >> 4;

    float* xcur = (k & 1) ? xB : xA;
    float* spa = (k & 1) ? SP1 : SP0;
    float* spz = (k & 1) ? SP0 : SP1;

    if (k > 0) {
        // ---------------- phase B(k-1): agg = L @ hT^T ; x update ----------------
        // 4-deep gload_lds pipeline: issue 3 tiles ahead, complete 1 ahead.
        u16* As = (u16*)smem;                  // 4 x 8192 B
        u16* Bs = (u16*)(smem + 32768);        // 4 x 16384 B
        float* red = (float*)smem;             // overlays As buf0 (dead after kt=12)
        const u16* gA = Lb + ((long)(bb * 1024 + n0)) * 1024;
        const u16* gB = hT + (long)bb * 131072;

        if (k <= 14 && (wg & 15) == 0 && t < 256) astore(&spz[bb * 256 + t], 0.f);

#define STAGE(buf, kt_) do {                                                  \
        int k0_ = (kt_) * 64;                                                 \
        { int u = t; int r = u >> 3, sl = u & 7;                              \
          gload16(gA + (long)r * 1024 + k0_ + ((sl ^ (r & 7)) << 3),          \
                  (char*)As + (buf) * 8192 + u * 16); }                       \
        _Pragma("unroll")                                                     \
        for (int j = 0; j < 2; ++j) {                                         \
            int u = t + 512 * j; int r = u >> 3, sl = u & 7;                  \
            gload16(gB + (long)r * 1024 + k0_ + ((sl ^ (r & 7)) << 3),        \
                    (char*)Bs + (buf) * 16384 + u * 16);                      \
        }                                                                     \
    } while (0)

        f32x4 acc[2][2] = {};
        STAGE(0, 0);
        STAGE(1, 1);
        STAGE(2, 2);
        asm volatile("s_waitcnt vmcnt(6)" ::: "memory");
        __builtin_amdgcn_s_barrier();

        for (int kt = 0; kt < 16; ++kt) {
            if (kt <= 12) STAGE((kt + 3) & 3, kt + 3);
            const char* Ab = (const char*)As + (kt & 3) * 8192;
            const char* Bb = (const char*)Bs + (kt & 3) * 16384;
            __builtin_amdgcn_s_setprio(1);
#pragma unroll
            for (int ks = 0; ks < 2; ++ks) {
                int kb = ks * 64 + ld16 * 16;
                bf16x8 af[2], bfr[2];
#pragma unroll
                for (int m = 0; m < 2; ++m) {
                    int r = wm * 32 + m * 16 + l16;
                    af[m] = *(const bf16x8*)(Ab + r * 128 + (kb ^ ((r & 7) << 4)));
                }
#pragma unroll
                for (int n = 0; n < 2; ++n) {
                    int e = wn * 32 + n * 16 + l16;
                    bfr[n] = *(const bf16x8*)(Bb + e * 128 + (kb ^ ((e & 7) << 4)));
                }
#pragma unroll
                for (int m = 0; m < 2; ++m)
#pragma unroll
                    for (int n = 0; n < 2; ++n)
                        acc[m][n] = __builtin_amdgcn_mfma_f32_16x16x32_bf16(
                            af[m], bfr[n], acc[m][n], 0, 0, 0);
            }
            __builtin_amdgcn_s_setprio(0);
            if (kt <= 12) {
                asm volatile("s_waitcnt vmcnt(6)" ::: "memory");
                __builtin_amdgcn_s_barrier();
            } else if (kt == 13) {
                asm volatile("s_waitcnt vmcnt(3)" ::: "memory");
                __builtin_amdgcn_s_barrier();
            } else if (kt == 14) {
                asm volatile("s_waitcnt vmcnt(0)" ::: "memory");
                __builtin_amdgcn_s_barrier();
            }
        }
#undef STAGE

        // epilogue: x1_new = x2_old + agg + bias ; stats partials
        float* dst = xcur + (long)wg * 8192;
        const float* biasv = bblk + (k - 1) * 128;
#pragma unroll
        for (int n = 0; n < 2; ++n) {
            int e = wn * 32 + n * 16 + l16;
            float bv = biasv[e];
            float sv = 0.f, qv = 0.f;
#pragma unroll
            for (int m = 0; m < 2; ++m) {
                int row0 = wm * 32 + m * 16 + ld16 * 4;
                float* dp = dst + (long)row0 * 128 + e;
#pragma unroll
                for (int j = 0; j < 4; ++j) {
                    float v = dp[j * 128] + acc[m][n][j] + bv;
                    dp[j * 128] = v;
                    sv += v; qv += v * v;
                }
            }
            red[(wm * 4 + ld16) * 128 + e] = sv;
            red[(8 + wm * 4 + ld16) * 128 + e] = qv;
        }
        __syncthreads();
        if (t < 128) {
            float a = 0;
#pragma unroll
            for (int g = 0; g < 8; ++g) a += red[g * 128 + t];
            atomicAdd(&spa[bb * 256 + t], a);
        } else if (t < 256) {
            int c = t - 128; float a = 0;
#pragma unroll
            for (int g = 0; g < 8; ++g) a += red[(8 + g) * 128 + c];
            atomicAdd(&spa[bb * 256 + 128 + c], a);
        }
        barw(bar, 256);
    }

    if (k < 15) {
        // ---------------- phase A(k): stats + BN+ELU + @W_k -> hT ----------------
        u16* Ws = (u16*)smem;               // [128][128] swz, 32KB
        u16* Hs = (u16*)(smem + 32768);     // [64][128] swz; reused CsT
        float* st = (float*)(smem + 49152);
        float* sc = (float*)(smem + 50176);
        float* sh = (float*)(smem + 50688);
        if (t < 256) {
            float s = 0.f;
#pragma unroll
            for (int i = 0; i < 16; ++i) s += aload(&spa[i * 256 + t]);
            st[t] = s;
        }
        const u32x4* wsrc = (const u32x4*)(WT + (size_t)k * 16384);
#pragma unroll
        for (int i = 0; i < 4; ++i) {
            int u = t + 512 * i;
            int r = u >> 4, sl = u & 15;
            *(u32x4*)((char*)Ws + r * 256 + ((sl ^ (r & 7)) << 4)) = wsrc[u];
        }
        __syncthreads();
        if (t < 128) {
            float mean = st[t] * INV_M, var = st[128 + t] * INV_M - mean * mean;
            float a = rsqrtf(var + EPSV) * gb[k * 128 + t];
            sc[t] = a; sh[t] = beb[k * 128 + t] - mean * a;
        }
        __syncthreads();
        const float* xb = xcur + (long)wg * 8192;
#pragma unroll
        for (int i = 0; i < 4; ++i) {
            int idx = t + 512 * i;
            int row = idx >> 5, c4 = (idx & 31) * 4;
            f32x4 v = *(const f32x4*)(xb + row * 128 + c4);
            float h0 = elu(v[0] * sc[c4]     + sh[c4]);
            float h1 = elu(v[1] * sc[c4 + 1] + sh[c4 + 1]);
            float h2 = elu(v[2] * sc[c4 + 2] + sh[c4 + 2]);
            float h3 = elu(v[3] * sc[c4 + 3] + sh[c4 + 3]);
            u32x2 pw = {pk2(h0, h1), pk2(h2, h3)};
            *(u32x2*)((char*)Hs + row * 256 + ((c4 * 2) ^ ((row & 7) << 4))) = pw;
        }
        __syncthreads();
        f32x4 acc[2][2] = {};
#pragma unroll
        for (int ks = 0; ks < 4; ++ks) {
            int kb = ks * 64 + ld16 * 16;
            bf16x8 af[2], bfr[2];
#pragma unroll
            for (int m = 0; m < 2; ++m) {
                int r = wm * 32 + m * 16 + l16;
                af[m] = *(const bf16x8*)((char*)Hs + r * 256 + (kb ^ ((r & 7) << 4)));
            }
#pragma unroll
            for (int n = 0; n < 2; ++n) {
                int e = wn * 32 + n * 16 + l16;
                bfr[n] = *(const bf16x8*)((char*)Ws + e * 256 + (kb ^ ((e & 7) << 4)));
            }
#pragma unroll
            for (int m = 0; m < 2; ++m)
#pragma unroll
                for (int n = 0; n < 2; ++n)
                    acc[m][n] = __builtin_amdgcn_mfma_f32_16x16x32_bf16(
                        af[m], bfr[n], acc[m][n], 0, 0, 0);
        }
        __syncthreads();
#pragma unroll
        for (int m = 0; m < 2; ++m)
#pragma unroll
            for (int n = 0; n < 2; ++n) {
                int e = wn * 32 + n * 16 + l16;
                int row0 = wm * 32 + m * 16 + ld16 * 4;
                u32x2 pw = {pk2(acc[m][n][0], acc[m][n][1]),
                            pk2(acc[m][n][2], acc[m][n][3])};
                *(u32x2*)((char*)Hs + e * 128 + ((row0 * 2) ^ ((e & 7) << 4))) = pw;
            }
        __syncthreads();
        {
            int e = t >> 2, sg = t & 3;
            const char* base = (const char*)Hs + e * 128;
            u16* orow = hT + ((long)(bb * 128 + e)) * 1024 + n0 + sg * 16;
#pragma unroll
            for (int u = 0; u < 2; ++u) {
                u32x4 v = *(const u32x4*)(base + ((sg * 32 + u * 16) ^ ((e & 7) << 4)));
                *(u32x4*)(orow + u * 8) = v;
            }
        }
    } else {
        // ---------------- final: BN1+BN2+ELU+masked pool + out ----------------
        float* x1p = xcur;                       // k=15 odd -> xB holds x1
        float* x2p = (k & 1) ? xA : xB;          // xA holds x2
        float* sc1 = (float*)smem;
        float* sh1 = sc1 + 128;
        float* sc2 = sh1 + 128;
        float* sh2 = sc2 + 128;
        float* msk = (float*)(smem + 2048);
        float* fred = (float*)(smem + 4096);
        if (t < 256) {
            int which = t >> 7, c = t & 127;
            const float* p = which ? SP0 : SP1;  // x1 stats in SP1, x2 in SP0
            float s = 0.f, q = 0.f;
#pragma unroll
            for (int i = 0; i < 16; ++i) {
                s += aload(&p[i * 256 + c]); q += aload(&p[i * 256 + 128 + c]);
            }
            float mean = s * INV_M, var = q * INV_M - mean * mean;
            float a = rsqrtf(var + EPSV) * (which ? g2[c] : g1[c]);
            (which ? sc2 : sc1)[c] = a;
            (which ? sh2 : sh1)[c] = (which ? be2[c] : be1[c]) - mean * a;
        } else if (t < 320) {
            msk[t - 256] = mask[bb * 1024 + n0 + (t - 256)];
        }
        __syncthreads();
        const float* xb1 = x1p + (long)wg * 8192;
        const float* xb2 = x2p + (long)wg * 8192;
        int row0 = t >> 5, c = (t & 31) * 4;
        f32x4 accv = {0.f, 0.f, 0.f, 0.f};
#pragma unroll
        for (int i = 0; i < 4; ++i) {
            int row = row0 + 16 * i;
            f32x4 v1 = *(const f32x4*)(xb1 + row * 128 + c);
            f32x4 v2 = *(const f32x4*)(xb2 + row * 128 + c);
            float m = msk[row];
            accv[0] += elu(v1[0]*sc1[c]   + sh1[c]   + v2[0]*sc2[c]   + sh2[c])   * m;
            accv[1] += elu(v1[1]*sc1[c+1] + sh1[c+1] + v2[1]*sc2[c+1] + sh2[c+1]) * m;
            accv[2] += elu(v1[2]*sc1[c+2] + sh1[c+2] + v2[2]*sc2[c+2] + sh2[c+2]) * m;
            accv[3] += elu(v1[3]*sc1[c+3] + sh1[c+3] + v2[3]*sc2[c+3] + sh2[c+3]) * m;
        }
        fred[row0 * 128 + c]     = accv[0];
        fred[row0 * 128 + c + 1] = accv[1];
        fred[row0 * 128 + c + 2] = accv[2];
        fred[row0 * 128 + c + 3] = accv[3];
        __syncthreads();
        if (t < 128) {
            float s = 0;
#pragma unroll
            for (int g = 0; g < 16; ++g) s += fred[g * 128 + t];
            astore(&poolP[wg * 128 + t], s);
        }
        if (t == 128) {
            float sm = 0;
#pragma unroll
            for (int j = 0; j < 64; ++j) sm += msk[j];
            astore(&maskP[wg], sm);
        }
        barw(bar, 256);
        if (wg < 16) {
            float* pooled = (float*)smem;
            __syncthreads();
            if (t < 128) {
                float s = 0.f;
                for (int tl = 0; tl < 16; ++tl)
                    s += aload(&poolP[(wg * 16 + tl) * 128 + t]);
                pooled[t] = s;
            }
            if (t == 128) {
                float sm = 0.f;
                for (int tl = 0; tl < 16; ++tl) sm += aload(&maskP[wg * 16 + tl]);
                pooled[128] = 1.f / sm;
            }
            __syncthreads();
            if (t < 128) {
                float acc = 0.f, inv = pooled[128];
                for (int d = 0; d < 128; ++d) acc += pooled[d] * W2[d * 128 + t];
                out[wg * 128 + t] = acc * inv + b2[t];
            }
        }
    }
}

// ---------------- host launcher ----------------

extern "C" void kernel_launch(void* const* d_in, const int* in_sizes, int n_in,
                              void* d_out, int out_size, void* d_ws, size_t ws_size,
                              hipStream_t stream) {
    const float* inputs = (const float*)d_in[0];
    const float* L      = (const float*)d_in[1];
    const float* mask   = (const float*)d_in[2];
    const float* W1     = (const float*)d_in[3];
    const float* b1     = (const float*)d_in[4];
    const float* Wb     = (const float*)d_in[5];
    const float* bblk   = (const float*)d_in[6];
    const float* gb     = (const float*)d_in[7];
    const float* beb    = (const float*)d_in[8];
    const float* g1     = (const float*)d_in[9];
    const float* be1    = (const float*)d_in[10];
    const float* g2     = (const float*)d_in[11];
    const float* be2    = (const float*)d_in[12];
    const float* W2     = (const float*)d_in[13];
    const float* b2     = (const float*)d_in[14];
    float* out = (float*)d_out;

    char* ws = (char*)d_ws;
    u16*      Lb    = (u16*)(ws);                      // 33554432 B
    u16*      WT    = (u16*)(ws + 33554432);           // 491520
    float*    xA    = (float*)(ws + 34045952);         // 8388608
    float*    xB    = (float*)(ws + 42434560);         // 8388608
    u16*      hT    = (u16*)(ws + 50823168);           // 4194304
    float*    poolP = (float*)(ws + 50823168);         // overlays hT (dead by then)
    float*    maskP = (float*)(ws + 50823168 + 131072);
    float*    SP0   = (float*)(ws + 55017472);         // 16384
    float*    SP1   = (float*)(ws + 55017472 + 16384); // 16384
    unsigned* bar   = (unsigned*)(ws + 55017472 + 32768);

    // zero SP0, SP1, barrier counter (in-graph, runs every replay)
    hipMemsetAsync(ws + 55017472, 0, 32768 + 1024, stream);

    hipLaunchKernelGGL(k_prep, dim3(2048), dim3(256), 0, stream,
                       inputs, L, W1, b1, Wb, Lb, WT, xA, xB, SP0);

    for (int k = 0; k <= 15; ++k) {
        hipLaunchKernelGGL(k_iter, dim3(256), dim3(512), 98304, stream, k,
                           mask, bblk, gb, beb, g1, be1, g2, be2, W2, b2,
                           Lb, WT, xA, xB, hT, SP0, SP1, bar, poolP, maskP, out);
    }
}